// Round 1
// 1568.555 us; speedup vs baseline: 1.1598x; 1.1598x over previous
//
#include <hip/hip_runtime.h>
#include <cstdint>
#include <cstddef>

#define B_SZ   4096
#define NF     26
#define VOC    100000
#define LDH    3088   // padded row stride of hmat (3072 flat + 13 dense + 3 pad)
#define DIN    3085

typedef __attribute__((ext_vector_type(8))) short short8;   // 8 bf16 (4 VGPRs)
typedef __attribute__((ext_vector_type(4))) float f32x4;

__device__ __forceinline__ float fast_tanh(float x) {
    float e = __expf(2.0f * x);
    return 1.0f - 2.0f * __builtin_amdgcn_rcpf(e + 1.0f);
}
__device__ __forceinline__ unsigned short f2bf(float x) {   // RNE float->bf16
    union { float f; unsigned u; } v; v.f = x;
    return (unsigned short)((v.u + 0x7FFFu + ((v.u >> 16) & 1u)) >> 16);
}
__device__ __forceinline__ unsigned short f2h(float x) {    // float->f16 (RNE)
    union { _Float16 h; unsigned short u; } v; v.h = (_Float16)x; return v.u;
}
__device__ __forceinline__ float h2f(unsigned short u) {    // f16->float
    union { unsigned short u; _Float16 h; } v; v.u = u; return (float)v.h;
}

// Batcher odd-even mergesort, valid for arbitrary N (ascending).
// Verified by hand for N=3,4,6. CE count: N=26 -> ~135, N=8 -> 19, N=7 -> 16, N=4 -> 5.
template<int N>
__device__ __forceinline__ void oem_sort(float (&a)[N]) {
#pragma unroll
    for (int p = 1; p < N; p <<= 1) {
#pragma unroll
        for (int k = p; k >= 1; k >>= 1) {
#pragma unroll
            for (int j = k % p; j + k < N; j += 2 * k) {
#pragma unroll
                for (int i = 0; i < k; ++i) {
                    int lo = i + j, hi = i + j + k;
                    if (hi < N && (lo / (2 * p) == hi / (2 * p))) {
                        float x = a[lo], y = a[hi];
                        a[lo] = fminf(x, y);
                        a[hi] = fmaxf(x, y);
                    }
                }
            }
        }
    }
}

// sort a bitonic sequence of 8 ascending (12 CE)
__device__ __forceinline__ void bclean8(float (&a)[8]) {
#pragma unroll
    for (int j = 4; j >= 1; j >>= 1) {
#pragma unroll
        for (int i = 0; i < 8; ++i) {
            if ((i & j) == 0 && (i | j) < 8) {
                float x = a[i], y = a[i + j];
                a[i] = fminf(x, y);
                a[i + j] = fmaxf(x, y);
            }
        }
    }
}
// sort a bitonic sequence of 4 ascending (4 CE)
__device__ __forceinline__ void bclean4(float (&a)[4]) {
#pragma unroll
    for (int j = 2; j >= 1; j >>= 1) {
#pragma unroll
        for (int i = 0; i < 4; ++i) {
            if ((i & j) == 0 && (i | j) < 4) {
                float x = a[i], y = a[i + j];
                a[i] = fminf(x, y);
                a[i + j] = fmaxf(x, y);
            }
        }
    }
}

// ---------------------------------------------------------------------------
// prep: conv weights -> MFMA-friendly layouts, zero BN accums, dense -> hmat
// ---------------------------------------------------------------------------
__global__ void prep_kernel(const float* __restrict__ cw1, const float* __restrict__ cw2,
                            const float* __restrict__ cw3, const float* __restrict__ dense,
                            float* __restrict__ w1t, unsigned short* __restrict__ w2b,
                            unsigned short* __restrict__ w3b, float* __restrict__ sums,
                            float* __restrict__ hmat)
{
    int idx = blockIdx.x * blockDim.x + threadIdx.x;
    if (idx < 448) {                       // cw1 (64,7) -> w1t[j*64+c]
        int c = idx / 7, j = idx % 7;
        w1t[j * 64 + c] = cw1[idx];
    } else if (idx < 10688) {              // cw2 (32,64,5) -> w2b[c2*320 + j*64+c]
        int o = idx - 448;
        int c2 = o / 320, k = o % 320;
        int j = k >> 6, c = k & 63;
        w2b[o] = f2bf(cw2[(c2 * 64 + c) * 5 + j]);
    } else if (idx < 12224) {              // cw3 (16,32,3) -> w3b[c3*96 + j*32+cc]
        int o = idx - 10688;
        int c3 = o / 96, k = o % 96;
        int j = k >> 5, cc = k & 31;
        w3b[o] = f2bf(cw3[(c3 * 32 + cc) * 3 + j]);
    } else if (idx < 12992) {              // zero BN accums (768)
        sums[idx - 12224] = 0.f;
    }
    int di = idx - 12992;
    if (di >= 0 && di < B_SZ * 13) {
        int b = di / 13, j = di % 13;
        hmat[(size_t)b * LDH + 3072 + j] = dense[di];
    }
}

// ---------------------------------------------------------------------------
// fused CNN: block = 256 thr (4 waves), 8 (b,d) pairs (same b, d0=blockIdx.x*8)
// Phase A: conv1 fp32 raw -> sort26 -> tanh top-23 -> t1s bf16
// Phase B: conv2 via MFMA 16x16x32 -> y2s f16 RAW (tanh deferred)
// Phase C: top-8 of 23 via merge-select -> tanh top-8 -> t2bf bf16
// Phase D: conv3 via MFMA -> y3s fp32 RAW (tanh deferred)
// Phase E: top-3 of 8 via merge-select -> tanh top-3 -> hmat
// ---------------------------------------------------------------------------
__global__ __launch_bounds__(256, 3) void cnn_kernel(
    const int* __restrict__ sparse, const float* __restrict__ tables,
    const float* __restrict__ w1t, const float* __restrict__ cb1,
    const unsigned short* __restrict__ w2b, const float* __restrict__ cb2,
    const unsigned short* __restrict__ w3b, const float* __restrict__ cb3,
    float* __restrict__ hmat)
{
    const int d0 = blockIdx.x * 8;
    const int b  = blockIdx.y;
    const int tid = threadIdx.x;

    __shared__ __align__(16) unsigned short t1s[8 * 1800]; // [dd][28][64c]+pad8
    __shared__ __align__(16) unsigned short y2s[8 * 32 * 25];
    __shared__ __align__(16) unsigned short t2bf[8 * 328]; // [dd][10][32cc]+pad8
    __shared__ __align__(16) float h0s[8 * 32];
    __shared__ __align__(16) float y3s[8 * 128];           // [dd][c3][8f]
    __shared__ int sidx[NF];

    if (tid < NF) sidx[tid] = sparse[b * NF + tid];
    __syncthreads();

    // ---- phase 0: zero pads + embedding gather ----
    for (int x = tid; x < 2560; x += 256) {      // t1s pads i in {0,1,25,26,27}
        int dd = x / 320, r = x % 320;
        int i5 = r >> 6, c = r & 63;
        int i = (i5 < 2) ? i5 : (23 + i5);
        t1s[dd * 1800 + i * 64 + c] = 0;
    }
    for (int x = tid; x < 512; x += 256) {       // t2bf pads i in {0,9}
        int dd = x >> 6, r = x & 63;
        int i = (r >> 5) * 9, cc = r & 31;
        t2bf[dd * 328 + i * 32 + cc] = 0;
    }
    if (tid < 48) {                              // h0s pads i in {0,1,2,29,30,31}
        int dd = tid / 6, r = tid % 6;
        int i = (r < 3) ? r : (26 + r);
        h0s[dd * 32 + i] = 0.f;
    } else {                                     // gather 26 feat x 8 dd
        int t = tid - 48;                        // t < 208
        if (t < 208) {
            int fi = t >> 3, dd = t & 7;
            h0s[dd * 32 + 3 + fi] =
                tables[((size_t)fi * VOC + sidx[fi]) * 64 + d0 + dd];
        }
    }
    __syncthreads();

    // ---- phase A: conv1 raw + sort26 + tanh on top-23 (512 tasks, 2/thread) ----
#pragma unroll
    for (int t = 0; t < 2; ++t) {
        int task = tid + 256 * t;
        int dd = task >> 6, c = task & 63;
        float w1r[7];
#pragma unroll
        for (int j = 0; j < 7; ++j) w1r[j] = w1t[j * 64 + c];
        float bias = cb1[c];
        float hr[32];
#pragma unroll
        for (int i = 0; i < 32; ++i) hr[i] = h0s[dd * 32 + i];
        float arr[26];
#pragma unroll
        for (int f = 0; f < 26; ++f) {
            float s = bias;
#pragma unroll
            for (int j = 0; j < 7; ++j) s += w1r[j] * hr[f + j];
            arr[f] = s;                           // raw: tanh deferred (monotone)
        }
        oem_sort<26>(arr);                        // ascending
        unsigned short* row = &t1s[dd * 1800 + c];
#pragma unroll
        for (int r = 0; r < 23; ++r) row[(2 + r) * 64] = f2bf(fast_tanh(arr[25 - r]));
    }
    __syncthreads();

    // ---- phase B: conv2 MFMA, store RAW acc as f16 ----
    {
        const int lane = tid & 63;
        const int w = tid >> 6;
        const int quad = lane >> 4;
        const int m = lane & 15;
        const int e = m >> 3, dd = m & 7;
        const int n = lane & 15;

        short8 Bf0[10], Bf1[10];
#pragma unroll
        for (int ks = 0; ks < 10; ++ks) {
            Bf0[ks] = *reinterpret_cast<const short8*>(w2b + (n * 320 + ks * 32 + quad * 8));
            Bf1[ks] = *reinterpret_cast<const short8*>(w2b + ((16 + n) * 320 + ks * 32 + quad * 8));
        }
        float bias0 = cb2[n], bias1 = cb2[16 + n];

#pragma unroll
        for (int pi = 0; pi < 3; ++pi) {
            int p = w + pi * 4;            // fpair 0..11
            int f0 = 2 * p;
            f32x4 acc0 = {bias0, bias0, bias0, bias0};
            f32x4 acc1 = {bias1, bias1, bias1, bias1};
            const unsigned short* abase = &t1s[dd * 1800 + (f0 + e) * 64 + quad * 8];
#pragma unroll
            for (int ks = 0; ks < 10; ++ks) {
                short8 af = *reinterpret_cast<const short8*>(abase + ks * 32);
                acc0 = __builtin_amdgcn_mfma_f32_16x16x32_bf16(af, Bf0[ks], acc0, 0, 0, 0);
                acc1 = __builtin_amdgcn_mfma_f32_16x16x32_bf16(af, Bf1[ks], acc1, 0, 0, 0);
            }
#pragma unroll
            for (int r = 0; r < 4; ++r) {
                int mm = quad * 4 + r;
                int ee = mm >> 3, dw = mm & 7;
                int f = f0 + ee;
                if (f < 23) {
                    y2s[(dw * 32 + n) * 25 + f]      = f2h(acc0[r]);
                    y2s[(dw * 32 + 16 + n) * 25 + f] = f2h(acc1[r]);
                }
            }
        }
    }
    __syncthreads();

    // ---- phase C: top-8 of 23 per (dd, c2) via sort8/sort8/sort7 + merge ----
    {
        int dd = tid >> 5, c2 = tid & 31;
        const unsigned short* src = &y2s[(dd * 32 + c2) * 25];
        float va[8], vb[8], vc[7];
#pragma unroll
        for (int f = 0; f < 8; ++f) va[f] = h2f(src[f]);
#pragma unroll
        for (int f = 0; f < 8; ++f) vb[f] = h2f(src[8 + f]);
#pragma unroll
        for (int f = 0; f < 7; ++f) vc[f] = h2f(src[16 + f]);
        oem_sort<8>(va);
        oem_sort<8>(vb);
        oem_sort<7>(vc);
        float mg[8];
#pragma unroll
        for (int i = 0; i < 8; ++i) mg[i] = fmaxf(va[i], vb[7 - i]); // top-8 set, bitonic
        bclean8(mg);
        float m2[8];
        m2[7] = mg[7];                                               // pad slot is -inf
#pragma unroll
        for (int i = 0; i < 7; ++i) m2[i] = fmaxf(mg[i], vc[6 - i]); // merge in third list
        bclean8(m2);
        unsigned short* row = &t2bf[dd * 328 + c2];
#pragma unroll
        for (int r = 0; r < 8; ++r) row[(1 + r) * 32] = f2bf(fast_tanh(m2[7 - r]));
    }
    __syncthreads();

    // ---- phase D: conv3 MFMA (wave w -> fpair w, f = 2w+e), store RAW fp32 ----
    {
        const int lane = tid & 63;
        const int w = tid >> 6;
        const int quad = lane >> 4;
        const int m = lane & 15;
        const int e = m >> 3, dd = m & 7;
        const int n = lane & 15;
        int f0 = 2 * w;

        f32x4 acc;
        float bias = cb3[n];
        acc[0] = bias; acc[1] = bias; acc[2] = bias; acc[3] = bias;
        const unsigned short* abase = &t2bf[dd * 328 + (f0 + e) * 32 + quad * 8];
#pragma unroll
        for (int ks = 0; ks < 3; ++ks) {
            short8 af = *reinterpret_cast<const short8*>(abase + ks * 32);
            short8 bf = *reinterpret_cast<const short8*>(w3b + (n * 96 + ks * 32 + quad * 8));
            acc = __builtin_amdgcn_mfma_f32_16x16x32_bf16(af, bf, acc, 0, 0, 0);
        }
#pragma unroll
        for (int r = 0; r < 4; ++r) {
            int mm = quad * 4 + r;
            int ee = mm >> 3, dw = mm & 7;
            int f = f0 + ee;
            y3s[dw * 128 + n * 8 + f] = acc[r];    // raw, tanh deferred
        }
    }
    __syncthreads();

    // ---- phase E: top-3 of 8 per (dd, c3) via sort4/sort4 + merge -> hmat ----
    if (tid < 128) {
        int dd = tid >> 4, c3 = tid & 15;
        const float* yb = &y3s[dd * 128 + c3 * 8];
        float a4[4], b4[4];
#pragma unroll
        for (int f = 0; f < 4; ++f) { a4[f] = yb[f]; b4[f] = yb[4 + f]; }
        oem_sort<4>(a4);
        oem_sort<4>(b4);
        float mg[4];
#pragma unroll
        for (int i = 0; i < 4; ++i) mg[i] = fmaxf(a4[i], b4[3 - i]);  // top-4 set, bitonic
        bclean4(mg);
        float* orow = &hmat[(size_t)b * LDH + c3 * 192 + d0 + dd];
        orow[0]   = fast_tanh(mg[3]);
        orow[64]  = fast_tanh(mg[2]);
        orow[128] = fast_tanh(mg[1]);
    }
}

// ---------------------------------------------------------------------------
// fp32 tiled GEMM: 32x64 tile, 256 thr -> 2 blocks/CU on gemm1 (was 1)
// ---------------------------------------------------------------------------
template<bool APPLY>
__global__ __launch_bounds__(256) void gemm_kernel(
    const float* __restrict__ A, int lda, int K,
    const float* __restrict__ Bm, int ldb,
    const float* __restrict__ scl, const float* __restrict__ sft,
    float* __restrict__ C, int N)
{
    __shared__ __align__(16) float As[16 * 36];   // [k][row], 32 rows + pad
    __shared__ __align__(16) float Bs[16 * 68];   // [k][n], 64 cols + pad
    const int tid = threadIdx.x;
    const int row0 = blockIdx.y * 32;
    const int n0 = blockIdx.x * 64;
    const int ty = tid >> 4, tx = tid & 15;

    float acc[2][4];
#pragma unroll
    for (int i = 0; i < 2; ++i)
#pragma unroll
        for (int j = 0; j < 4; ++j) acc[i][j] = 0.f;

    const int kk_a = tid & 15, rb_a = tid >> 4;
    const int kr_b = tid >> 4, nb_b = (tid & 15) * 4;

    for (int k0 = 0; k0 < K; k0 += 16) {
        __syncthreads();
        {
            int k = k0 + kk_a;
            bool ok = (k < K);
            float sc = 0.f, sh = 0.f;
            if (APPLY && ok) { sc = scl[k]; sh = sft[k]; }
#pragma unroll
            for (int p = 0; p < 2; ++p) {
                int r = rb_a + p * 16;
                float v = 0.f;
                if (ok) {
                    v = A[(size_t)(row0 + r) * lda + k];
                    if (APPLY) v = fast_tanh(v * sc + sh);
                }
                As[kk_a * 36 + r] = v;
            }
        }
        {
            int k = k0 + kr_b;
            float4 bv = make_float4(0.f, 0.f, 0.f, 0.f);
            if (k < K) bv = *reinterpret_cast<const float4*>(&Bm[(size_t)k * ldb + n0 + nb_b]);
            *reinterpret_cast<float4*>(&Bs[kr_b * 68 + nb_b]) = bv;
        }
        __syncthreads();
#pragma unroll
        for (int kk = 0; kk < 16; ++kk) {
            float2 av = *reinterpret_cast<const float2*>(&As[kk * 36 + ty * 2]);
            float4 bv = *reinterpret_cast<const float4*>(&Bs[kk * 68 + tx * 4]);
            float bb[4] = {bv.x, bv.y, bv.z, bv.w};
#pragma unroll
            for (int j = 0; j < 4; ++j) {
                acc[0][j] += av.x * bb[j];
                acc[1][j] += av.y * bb[j];
            }
        }
    }

#pragma unroll
    for (int i = 0; i < 2; ++i) {
        float4 ov = make_float4(acc[i][0], acc[i][1], acc[i][2], acc[i][3]);
        *reinterpret_cast<float4*>(&C[(size_t)(row0 + ty * 2 + i) * N + n0 + tx * 4]) = ov;
    }
}

// 16 rows per block (grid 256), blockDim MUST equal ncols (fixes z2 OOB pollution)
__global__ void bnstats_kernel(const float* __restrict__ z, int ncols,
                               float* __restrict__ sums, float* __restrict__ sumsq)
{
    int col = threadIdx.x;
    int r0 = blockIdx.x * 16;
    float s = 0.f, q = 0.f;
#pragma unroll
    for (int i = 0; i < 16; ++i) {
        float v = z[(size_t)(r0 + i) * ncols + col];
        s += v; q += v * v;
    }
    atomicAdd(&sums[col], s);
    atomicAdd(&sumsq[col], q);
}

__global__ void bnfin_kernel(const float* __restrict__ sums, const float* __restrict__ sumsq,
                             const float* __restrict__ g, const float* __restrict__ be,
                             int ncols, float* __restrict__ scl, float* __restrict__ sft)
{
    int i = threadIdx.x + blockIdx.x * blockDim.x;
    if (i < ncols) {
        float mu = sums[i] * (1.0f / 4096.0f);
        float var = sumsq[i] * (1.0f / 4096.0f) - mu * mu;
        float s = g[i] * rsqrtf(var + 1e-5f);
        scl[i] = s;
        sft[i] = be[i] - mu * s;
    }
}

__global__ __launch_bounds__(256) void final_kernel(
    const float* __restrict__ z2, const float* __restrict__ scl, const float* __restrict__ sft,
    const float* __restrict__ W3, const float* __restrict__ b3, float* __restrict__ out)
{
    int lane = threadIdx.x & 63;
    int wv = threadIdx.x >> 6;
    int r = blockIdx.x * 4 + wv;
    float p = 0.f;
#pragma unroll
    for (int t = 0; t < 2; ++t) {
        int n = lane + t * 64;
        p += fast_tanh(z2[(size_t)r * 128 + n] * scl[n] + sft[n]) * W3[n];
    }
#pragma unroll
    for (int off = 32; off > 0; off >>= 1) p += __shfl_down(p, off);
    if (lane == 0) out[r] = p + b3[0];
}

extern "C" void kernel_launch(void* const* d_in, const int* in_sizes, int n_in,
                              void* d_out, int out_size, void* d_ws, size_t ws_size,
                              hipStream_t stream) {
    const int*   sparse = (const int*)  d_in[0];
    const float* dense  = (const float*)d_in[1];
    const float* tables = (const float*)d_in[2];
    const float* cw1    = (const float*)d_in[3];
    const float* cb1    = (const float*)d_in[4];
    const float* cw2    = (const float*)d_in[5];
    const float* cb2    = (const float*)d_in[6];
    const float* cw3    = (const float*)d_in[7];
    const float* cb3    = (const float*)d_in[8];
    const float* W1     = (const float*)d_in[9];
    const float* g1     = (const float*)d_in[11];
    const float* be1    = (const float*)d_in[12];
    const float* W2     = (const float*)d_in[13];
    const float* g2     = (const float*)d_in[15];
    const float* be2    = (const float*)d_in[16];
    const float* W3     = (const float*)d_in[17];
    const float* b3     = (const float*)d_in[18];
    float* out = (float*)d_out;

    float* ws   = (float*)d_ws;
    float* hmat = ws;                                  // 4096*3088
    float* z1   = hmat + (size_t)B_SZ * LDH;           // 4096*256
    float* z2   = z1 + (size_t)B_SZ * 256;             // 4096*128
    float* w1t  = z2 + (size_t)B_SZ * 128;             // 448 fp32
    unsigned short* w2b = (unsigned short*)(w1t + 448);    // 10240 bf16 (5120 f)
    unsigned short* w3b = (unsigned short*)(w1t + 448 + 5120); // 1536 bf16 (768 f)
    float* sums = w1t + 448 + 5120 + 768;              // 768
    float* a1   = sums + 768;                          // 256
    float* c1   = a1 + 256;                            // 256
    float* a2   = c1 + 256;                            // 128
    float* c2v  = a2 + 128;                            // 128

    prep_kernel<<<259, 256, 0, stream>>>(cw1, cw2, cw3, dense, w1t, w2b, w3b, sums, hmat);

    cnn_kernel<<<dim3(8, B_SZ), 256, 0, stream>>>(sparse, tables, w1t, cb1,
                                                  w2b, cb2, w3b, cb3, hmat);

    gemm_kernel<false><<<dim3(4, 128), 256, 0, stream>>>(hmat, LDH, DIN, W1, 256,
                                                         nullptr, nullptr, z1, 256);
    bnstats_kernel<<<256, 256, 0, stream>>>(z1, 256, sums, sums + 256);
    bnfin_kernel<<<1, 256, 0, stream>>>(sums, sums + 256, g1, be1, 256, a1, c1);

    gemm_kernel<true><<<dim3(2, 128), 256, 0, stream>>>(z1, 256, 256, W2, 128,
                                                        a1, c1, z2, 128);
    bnstats_kernel<<<256, 128, 0, stream>>>(z2, 128, sums + 512, sums + 640);
    bnfin_kernel<<<1, 128, 0, stream>>>(sums + 512, sums + 640, g2, be2, 128, a2, c2v);

    final_kernel<<<1024, 256, 0, stream>>>(z2, a2, c2v, W3, b3, out);
}